// Round 8
// baseline (88.265 us; speedup 1.0000x reference)
//
#include <hip/hip_runtime.h>
#include <array>

// Problem constants (fixed by reference setup_inputs)
constexpr int Cc   = 3;
constexpr int Hc   = 160;
constexpr int Wc   = 160;
constexpr int Hoc  = 158;
constexpr int Woc  = 158;
constexpr int Lc   = Hoc * Woc;    // 24964
constexpr int Ntot = 4 * Lc;       // 99856
constexpr int NCH  = 8;
constexpr int MDd  = 54;           // 2 * C * 3 * 3

// ---------------------------------------------------------------------------
// Batcher odd-even mergesort network for n=64, pruned to wires < 54 (monotone
// network; pruned wires are implicit -inf pads under the descending
// comparator). Same structure proven correct in rounds 0-4/6/7.
// ---------------------------------------------------------------------------
struct CEpair { unsigned char lo, hi; };

constexpr int count_ces() {
    int cnt = 0;
    for (int p = 1; p < 64; p <<= 1)
        for (int k = p; k >= 1; k >>= 1)
            for (int j = k % p; j + k < 64; j += 2 * k)
                for (int i = 0; i < k; ++i) {
                    const int lo = i + j, hi = i + j + k;
                    if (hi < MDd && (lo / (2 * p) == hi / (2 * p))) ++cnt;
                }
    return cnt;
}
constexpr int NCE = count_ces();

constexpr std::array<CEpair, NCE> make_net() {
    std::array<CEpair, NCE> a{};
    int cnt = 0;
    for (int p = 1; p < 64; p <<= 1)
        for (int k = p; k >= 1; k >>= 1)
            for (int j = k % p; j + k < 64; j += 2 * k)
                for (int i = 0; i < k; ++i) {
                    const int lo = i + j, hi = i + j + k;
                    if (hi < MDd && (lo / (2 * p) == hi / (2 * p))) {
                        a[cnt].lo = (unsigned char)lo;
                        a[cnt].hi = (unsigned char)hi;
                        ++cnt;
                    }
                }
    return a;
}
constexpr auto NET = make_net();

// F64-PACKED compare-exchange (round 7, verified absmax 0.0 and ~36 us):
// each sort element is ONE double whose bit pattern is
// (f32 key bits << 32) | (f32 weight bits).
//
// Monotone embedding: for distinct f32 keys a,b, f64-compare of (a<<32|x) vs
// (b<<32|y) equals the f32 value compare (both sign-magnitude orders; f32 Inf
// widens to a huge FINITE f64; f64 NaN would require an f32 NaN key,
// impossible from finite x+mask sums). Exact-key ties are broken by weight
// bits; tied keys carry equal values so the selected OUTPUT is unaffected
// (verified: absmax 0.0 on the fixed dataset).
//
// CE = v_max_f64 + v_min_f64: 2 instructions, no vcc, payload rides free.
// Round-7 timing (~36 us = exactly the shuttle-free arithmetic) confirms the
// AGPR<->VGPR shuttle tax of rounds 0-6 is GONE with f64 pairs.
// Kept as inline asm: round 2 measured plain-C CEs letting the scheduler
// inflate live ranges into a 22x scratch-spill catastrophe.
__device__ __forceinline__ void ce(double &a, double &b) {
    double hi, lo;
    asm("v_max_f64 %0, %2, %3\n\t"
        "v_min_f64 %1, %2, %3"
        : "=&v"(hi), "=v"(lo)
        : "v"(a), "v"(b));
    a = hi; b = lo;
}

// Fences: scratch-spill guard (bounds scheduler live-range inflation);
// verified effective in rounds 4/6/7.
constexpr int FENCE_EVERY = 16;

// (256,4): 128-reg budget, 4 waves/SIMD. State is ~110 regs (54 f64 pairs +
// temps); per-c build fences below cap in-flight temps at ~13 so peak ~123
// fits. Round 7 ran (256,3) at ~36 us with ~20% issue-idle; 4 waves/SIMD
// targets that idle. Tripwire: WRITE_SIZE >> 6.24 MB means the allocator
// spilled to meet the bound -> revert to (256,3).
__global__ __launch_bounds__(256, 4) void wos_kernel(
    const float* __restrict__ x, const float* __restrict__ weight,
    const float* __restrict__ bias, const float* __restrict__ mask,
    float* __restrict__ out)
{
    const int lane = threadIdx.x & 63;
    const int wave = threadIdx.x >> 6;
    const int grp  = blockIdx.x >> 1;
    // nc is wave-uniform: assert it so weight/mask/bias reads become scalar loads.
    const int nc   = __builtin_amdgcn_readfirstlane(((blockIdx.x & 1) << 2) | wave);
    const int n    = grp * 64 + lane;
    if (n >= Ntot) return;

    const int b  = n / Lc;
    const int l  = n - b * Lc;
    const int ho = l / Woc;
    const int wo = l - ho * Woc;

    const float* xb = x + (b * Cc) * (Hc * Wc);
    const float* mk = mask + nc * MDd;      // wave-uniform -> scalar loads
    const float* wr = weight + nc * MDd;    // wave-uniform -> scalar loads
    const float  bi = bias[nc];

    // Build packed elements: high word = raw bits of key (mx value), low word
    // = raw bits of weight. mk[27+d] - v == (-v) + mk[27+d] bit-exactly.
    // Fence after each c-block: caps in-flight build temps (9 loads + addr)
    // so peak pressure stays under the 128-reg budget.
    double key[MDd];
    #pragma unroll
    for (int c = 0; c < 3; ++c) {
        #pragma unroll
        for (int r = 0; r < 3; ++r) {
            #pragma unroll
            for (int s = 0; s < 3; ++s) {
                const int d = c * 9 + r * 3 + s;
                const float v = xb[(c * Hc + ho + r) * Wc + wo + s];
                const unsigned long long kp =
                    ((unsigned long long)__float_as_uint(v + mk[d]) << 32) |
                    __float_as_uint(wr[d]);
                const unsigned long long kn =
                    ((unsigned long long)__float_as_uint(mk[27 + d] - v) << 32) |
                    __float_as_uint(wr[27 + d]);
                key[d]      = __longlong_as_double((long long)kp);
                key[27 + d] = __longlong_as_double((long long)kn);
            }
        }
        __builtin_amdgcn_sched_barrier(0);
    }

    // Flattened sorting network. After full unroll every NET[ci] index is a
    // compile-time constant (array stays in registers).
    #pragma unroll
    for (int ci = 0; ci < NCE; ++ci) {
        ce(key[NET[ci].lo], key[NET[ci].hi]);
        if (ci % FENCE_EVERY == FENCE_EVERY - 1)
            __builtin_amdgcn_sched_barrier(0);
    }
    __builtin_amdgcn_sched_barrier(0);   // sort may not bleed into the cumsum

    // Sequential fp32 cumsum of the (exact, raw-bits) weights in sorted
    // descending-key order — bit-matches the reference summation. Track the
    // key of the last rank whose cumulative weight <= bias; default rank 0.
    const unsigned long long u0 =
        (unsigned long long)__double_as_longlong(key[0]);
    float acc = 0.0f;
    float sel = __uint_as_float((unsigned)(u0 >> 32));
    #pragma unroll
    for (int r = 0; r < MDd; ++r) {
        const unsigned long long u =
            (unsigned long long)__double_as_longlong(key[r]);
        acc += __uint_as_float((unsigned)u);            // low word: weight
        const float kv = __uint_as_float((unsigned)(u >> 32)); // high: key
        sel = (acc <= bi) ? kv : sel;
    }

    out[n * NCH + nc] = sel;
}

extern "C" void kernel_launch(void* const* d_in, const int* in_sizes, int n_in,
                              void* d_out, int out_size, void* d_ws, size_t ws_size,
                              hipStream_t stream) {
    const float* x      = (const float*)d_in[0];
    const float* weight = (const float*)d_in[1];
    const float* bias   = (const float*)d_in[2];
    const float* mask   = (const float*)d_in[3];
    float* out = (float*)d_out;

    const int ngrp = (Ntot + 63) / 64;      // 1561
    dim3 grid(ngrp * 2);                    // x2 blocks: 8 nc / 4 waves
    wos_kernel<<<grid, 256, 0, stream>>>(x, weight, bias, mask, out);
}

// Round 9
// 86.594 us; speedup vs baseline: 1.0193x; 1.0193x over previous
//
#include <hip/hip_runtime.h>
#include <array>

// Problem constants (fixed by reference setup_inputs)
constexpr int Cc   = 3;
constexpr int Hc   = 160;
constexpr int Wc   = 160;
constexpr int Hoc  = 158;
constexpr int Woc  = 158;
constexpr int Lc   = Hoc * Woc;    // 24964
constexpr int Ntot = 4 * Lc;       // 99856
constexpr int NCH  = 8;
constexpr int MDd  = 54;           // 2 * C * 3 * 3

// ---------------------------------------------------------------------------
// Batcher odd-even mergesort network for n=64, pruned to wires < 54 (monotone
// network; pruned wires are implicit -inf pads under the descending
// comparator). Same structure proven correct in rounds 0-4/6/7/8.
// ---------------------------------------------------------------------------
struct CEpair { unsigned char lo, hi; };

constexpr int count_ces() {
    int cnt = 0;
    for (int p = 1; p < 64; p <<= 1)
        for (int k = p; k >= 1; k >>= 1)
            for (int j = k % p; j + k < 64; j += 2 * k)
                for (int i = 0; i < k; ++i) {
                    const int lo = i + j, hi = i + j + k;
                    if (hi < MDd && (lo / (2 * p) == hi / (2 * p))) ++cnt;
                }
    return cnt;
}
constexpr int NCE = count_ces();

constexpr std::array<CEpair, NCE> make_net() {
    std::array<CEpair, NCE> a{};
    int cnt = 0;
    for (int p = 1; p < 64; p <<= 1)
        for (int k = p; k >= 1; k >>= 1)
            for (int j = k % p; j + k < 64; j += 2 * k)
                for (int i = 0; i < k; ++i) {
                    const int lo = i + j, hi = i + j + k;
                    if (hi < MDd && (lo / (2 * p) == hi / (2 * p))) {
                        a[cnt].lo = (unsigned char)lo;
                        a[cnt].hi = (unsigned char)hi;
                        ++cnt;
                    }
                }
    return a;
}
constexpr auto NET = make_net();

// F64-PACKED compare-exchange (round 7, verified absmax 0.0, ~36 us kernel):
// each sort element is ONE double whose bit pattern is
// (f32 key bits << 32) | (f32 weight bits).
//
// Monotone embedding: for distinct f32 keys a,b, f64-compare of (a<<32|x) vs
// (b<<32|y) equals the f32 value compare (both sign-magnitude orders; f32 Inf
// widens to a huge FINITE f64; f64 NaN would require an f32 NaN key,
// impossible from finite x+mask sums). Exact-key ties are broken by weight
// bits; tied keys carry equal values so the selected OUTPUT is unaffected.
//
// CE = v_max_f64 + v_min_f64: 2 instructions, no vcc, payload rides free.
// Round-7 timing (~36 us = the shuttle-free cycle arithmetic) confirms the
// AGPR<->VGPR shuttle tax of rounds 0-6 is gone with f64 pairs.
// Kept as inline asm: round 2 measured plain-C CEs letting the scheduler
// inflate live ranges into a 22x scratch-spill catastrophe.
__device__ __forceinline__ void ce(double &a, double &b) {
    double hi, lo;
    asm("v_max_f64 %0, %2, %3\n\t"
        "v_min_f64 %1, %2, %3"
        : "=&v"(hi), "=v"(lo)
        : "v"(a), "v"(b));
    a = hi; b = lo;
}

// Fences: scratch-spill guard (bounds scheduler live-range inflation);
// verified effective in rounds 4/6/7.
constexpr int FENCE_EVERY = 16;

// (256,3): the measured-best config (round 7: 86.8 us harness). Round 8
// tested (256,4) + per-c build fences: neutral-to-negative (88.3 us) — this
// kernel has no memory latency to hide, so the 4th wave buys nothing and the
// tighter budget slightly degrades the schedule. Reverted.
__global__ __launch_bounds__(256, 3) void wos_kernel(
    const float* __restrict__ x, const float* __restrict__ weight,
    const float* __restrict__ bias, const float* __restrict__ mask,
    float* __restrict__ out)
{
    const int lane = threadIdx.x & 63;
    const int wave = threadIdx.x >> 6;
    const int grp  = blockIdx.x >> 1;
    // nc is wave-uniform: assert it so weight/mask/bias reads become scalar loads.
    const int nc   = __builtin_amdgcn_readfirstlane(((blockIdx.x & 1) << 2) | wave);
    const int n    = grp * 64 + lane;
    if (n >= Ntot) return;

    const int b  = n / Lc;
    const int l  = n - b * Lc;
    const int ho = l / Woc;
    const int wo = l - ho * Woc;

    const float* xb = x + (b * Cc) * (Hc * Wc);
    const float* mk = mask + nc * MDd;      // wave-uniform -> scalar loads
    const float* wr = weight + nc * MDd;    // wave-uniform -> scalar loads
    const float  bi = bias[nc];

    // Build packed elements: high word = raw bits of key (mx value), low word
    // = raw bits of weight. mk[27+d] - v == (-v) + mk[27+d] bit-exactly.
    double key[MDd];
    #pragma unroll
    for (int c = 0; c < 3; ++c) {
        #pragma unroll
        for (int r = 0; r < 3; ++r) {
            #pragma unroll
            for (int s = 0; s < 3; ++s) {
                const int d = c * 9 + r * 3 + s;
                const float v = xb[(c * Hc + ho + r) * Wc + wo + s];
                const unsigned long long kp =
                    ((unsigned long long)__float_as_uint(v + mk[d]) << 32) |
                    __float_as_uint(wr[d]);
                const unsigned long long kn =
                    ((unsigned long long)__float_as_uint(mk[27 + d] - v) << 32) |
                    __float_as_uint(wr[27 + d]);
                key[d]      = __longlong_as_double((long long)kp);
                key[27 + d] = __longlong_as_double((long long)kn);
            }
        }
    }
    __builtin_amdgcn_sched_barrier(0);   // build may not bleed into the sort

    // Flattened sorting network. After full unroll every NET[ci] index is a
    // compile-time constant (array stays in registers).
    #pragma unroll
    for (int ci = 0; ci < NCE; ++ci) {
        ce(key[NET[ci].lo], key[NET[ci].hi]);
        if (ci % FENCE_EVERY == FENCE_EVERY - 1)
            __builtin_amdgcn_sched_barrier(0);
    }
    __builtin_amdgcn_sched_barrier(0);   // sort may not bleed into the cumsum

    // Sequential fp32 cumsum of the (exact, raw-bits) weights in sorted
    // descending-key order — bit-matches the reference summation. Track the
    // key of the last rank whose cumulative weight <= bias; default rank 0.
    const unsigned long long u0 =
        (unsigned long long)__double_as_longlong(key[0]);
    float acc = 0.0f;
    float sel = __uint_as_float((unsigned)(u0 >> 32));
    #pragma unroll
    for (int r = 0; r < MDd; ++r) {
        const unsigned long long u =
            (unsigned long long)__double_as_longlong(key[r]);
        acc += __uint_as_float((unsigned)u);            // low word: weight
        const float kv = __uint_as_float((unsigned)(u >> 32)); // high: key
        sel = (acc <= bi) ? kv : sel;
    }

    out[n * NCH + nc] = sel;
}

extern "C" void kernel_launch(void* const* d_in, const int* in_sizes, int n_in,
                              void* d_out, int out_size, void* d_ws, size_t ws_size,
                              hipStream_t stream) {
    const float* x      = (const float*)d_in[0];
    const float* weight = (const float*)d_in[1];
    const float* bias   = (const float*)d_in[2];
    const float* mask   = (const float*)d_in[3];
    float* out = (float*)d_out;

    const int ngrp = (Ntot + 63) / 64;      // 1561
    dim3 grid(ngrp * 2);                    // x2 blocks: 8 nc / 4 waves
    wos_kernel<<<grid, 256, 0, stream>>>(x, weight, bias, mask, out);
}